// Round 12
// baseline (91.884 us; speedup 1.0000x reference)
//
#include <hip/hip_runtime.h>

#define RNK 32
#define VOC 32000
#define BSZ 512
#define SEQ 24

#define RED_BLOCKS 4000           // 32 r-slabs x 125 chunks
#define RED_THREADS 256
#define DEPTH 4                   // tokens in flight per chain wave
#define NSLOT 5                   // DEPTH+1 -> rotation never aliases (absmax-0 proven)

// ws layout: gm[1024]f32 | bitmap[1024]u32 | staged[VOC][32][32] bf16 (65.5 MB)
#define WS_NEEDED ((size_t)8192 + (size_t)VOC * 1024 * 2)

typedef const __attribute__((address_space(1))) void* as1_cvp;
typedef __attribute__((address_space(3))) void* as3_vp;

// ===========================================================================
// STAGED PATH
// ===========================================================================

// Token-usage bitmap: 12288 tokens -> 1024 words. 48 blocks x 256.
__global__ __launch_bounds__(256) void bitmap_kernel(const int* __restrict__ y,
                                                     unsigned* __restrict__ bitmap) {
    const int tok = y[blockIdx.x * 256 + threadIdx.x];
    atomicOr(&bitmap[tok >> 5], 1u << (tok & 31));
}

// Stream core: gm reduction (register butterfly, proven) + export used tokens'
// rows as bf16 FROM THE STREAMED REGISTERS (no re-read). Thread (tid,i) holds
// (v = chunk*256 + i*32 + tid/8, s = (tid&7)*4 ..+3) of slab r. One
// block-uniform bitmap word per iteration; one predicated 8-B store.
__global__ __launch_bounds__(RED_THREADS) void reduce_stage_kernel(
        const float* __restrict__ core, float* __restrict__ gm,
        const unsigned* __restrict__ bitmap, unsigned short* __restrict__ staged) {
    const int bid   = blockIdx.x;
    const int r     = bid & 31;
    const int chunk = bid >> 5;               // 0..124
    const int tid   = threadIdx.x;

    const float4* slab = (const float4*)(core + (size_t)r * VOC * RNK);
    const int base = chunk * 2048 + tid;      // float4 index
    const int vloc = tid >> 3;                // v within this iteration's 32-group
    const int s0   = (tid & 7) * 4;

    float a0 = 0.f, a1 = 0.f, a2 = 0.f, a3 = 0.f;
    #pragma unroll
    for (int i = 0; i < 8; ++i) {
        const float4 v = slab[base + i * 256];
        a0 += v.x; a1 += v.y; a2 += v.z; a3 += v.w;
        const unsigned w = bitmap[chunk * 8 + i];        // block-uniform word
        if (w & (1u << vloc)) {
            const int vidx = chunk * 256 + i * 32 + vloc;
            ushort4 h;
            h.x = (unsigned short)(__float_as_uint(v.x) >> 16);   // bf16 truncate
            h.y = (unsigned short)(__float_as_uint(v.y) >> 16);
            h.z = (unsigned short)(__float_as_uint(v.z) >> 16);
            h.w = (unsigned short)(__float_as_uint(v.w) >> 16);
            *(ushort4*)(staged + (size_t)vidx * 1024 + r * 32 + s0) = h;
        }
    }

    // s-phase (tid&7)*4 invariant under xor 8/16/32 [proven]
    #pragma unroll
    for (int mask = 8; mask <= 32; mask <<= 1) {
        a0 += __shfl_xor(a0, mask, 64);
        a1 += __shfl_xor(a1, mask, 64);
        a2 += __shfl_xor(a2, mask, 64);
        a3 += __shfl_xor(a3, mask, 64);
    }
    if ((tid & 63) < 8) {
        const int q = (tid & 7) * 4;
        atomicAdd(&gm[r * RNK + q + 0], a0);
        atomicAdd(&gm[r * RNK + q + 1], a1);
        atomicAdd(&gm[r * RNK + q + 2], a2);
        atomicAdd(&gm[r * RNK + q + 3], a3);
    }
}

// Chain from staged: each token matrix is ONE contiguous 2 KB read
// (2 x global_load_lds dwordx4). DEPTH-4 / NSLOT-5 alias-free schedule.
// Block BSZ computes z from gm (kernel-boundary ordered).
__global__ __launch_bounds__(64) void chainz_staged_kernel(
        const unsigned short* __restrict__ staged, const int* __restrict__ y,
        const float* __restrict__ alpha, const float* __restrict__ beta,
        const float* __restrict__ gm, float* __restrict__ out) {
    __shared__ unsigned short mbufh[NSLOT * 1024];       // 10 KB
    const int tid = threadIdx.x;                          // == lane

    if (blockIdx.x < BSZ) {
        const int lane = tid;
        const int s    = lane & 31;
        const int half = lane >> 5;
        const int row  = blockIdx.x;

        int ytok = (lane < SEQ) ? y[row * SEQ + lane] : 0;
        float state = alpha[s];
        const float betav = beta[s];

        asm volatile("s_waitcnt vmcnt(0)" ::: "memory");  // vmcnt counts gl_lds only

        #pragma unroll
        for (int pt = 0; pt < DEPTH; ++pt) {              // tokens 0..3 -> slots 0..3
            const int tok = __shfl(ytok, pt, 64);
            const unsigned short* src = staged + (size_t)tok * 1024;
            #pragma unroll
            for (int j = 0; j < 2; ++j)
                __builtin_amdgcn_global_load_lds((as1_cvp)(src + j * 512 + lane * 8),
                                                 (as3_vp)(mbufh + pt * 1024 + j * 512), 16, 0, 0);
        }

        #pragma unroll
        for (int t = 0; t < SEQ; ++t) {                   // literal waits (2 ops/token)
            if      (t <= SEQ - 4) asm volatile("s_waitcnt vmcnt(6)" ::: "memory");
            else if (t == SEQ - 3) asm volatile("s_waitcnt vmcnt(4)" ::: "memory");
            else if (t == SEQ - 2) asm volatile("s_waitcnt vmcnt(2)" ::: "memory");
            else                   asm volatile("s_waitcnt vmcnt(0)" ::: "memory");
            __builtin_amdgcn_sched_barrier(0);

            const unsigned short* M = mbufh + (t % NSLOT) * 1024;
            float a0 = 0.f, a1 = 0.f, a2 = 0.f, a3 = 0.f;
            #pragma unroll
            for (int i = 0; i < 16; i += 4) {
                a0 = fmaf(__shfl(state, half*16+i+0, 64), __uint_as_float((unsigned)M[(half*16+i+0)*32+s] << 16), a0);
                a1 = fmaf(__shfl(state, half*16+i+1, 64), __uint_as_float((unsigned)M[(half*16+i+1)*32+s] << 16), a1);
                a2 = fmaf(__shfl(state, half*16+i+2, 64), __uint_as_float((unsigned)M[(half*16+i+2)*32+s] << 16), a2);
                a3 = fmaf(__shfl(state, half*16+i+3, 64), __uint_as_float((unsigned)M[(half*16+i+3)*32+s] << 16), a3);
            }
            const float acc = (a0 + a1) + (a2 + a3);
            state = acc + __shfl_xor(acc, 32, 64);

            if (t + DEPTH < SEQ) {
                const int tok = __shfl(ytok, t + DEPTH, 64);
                const unsigned short* src = staged + (size_t)tok * 1024;
                unsigned short* dst = mbufh + ((t + DEPTH) % NSLOT) * 1024;
                #pragma unroll
                for (int j = 0; j < 2; ++j)
                    __builtin_amdgcn_global_load_lds((as1_cvp)(src + j * 512 + lane * 8),
                                                     (as3_vp)(dst + j * 512), 16, 0, 0);
            }
        }

        float p = state * betav;
        #pragma unroll
        for (int m = 16; m >= 1; m >>= 1) p += __shfl_xor(p, m, 64);
        if (lane == 0) out[row] = p;
    } else {
        const int s    = tid & 31;
        const int half = tid >> 5;
        float col[16];
        #pragma unroll
        for (int i = 0; i < 16; ++i) col[i] = gm[(half * 16 + i) * RNK + s];
        float v = alpha[s];
        #pragma unroll
        for (int t = 0; t < SEQ; ++t) {
            float a0 = 0.f, a1 = 0.f, a2 = 0.f, a3 = 0.f;
            #pragma unroll
            for (int i = 0; i < 16; i += 4) {
                a0 = fmaf(__shfl(v, half * 16 + i + 0, 64), col[i + 0], a0);
                a1 = fmaf(__shfl(v, half * 16 + i + 1, 64), col[i + 1], a1);
                a2 = fmaf(__shfl(v, half * 16 + i + 2, 64), col[i + 2], a2);
                a3 = fmaf(__shfl(v, half * 16 + i + 3, 64), col[i + 3], a3);
            }
            const float acc = (a0 + a1) + (a2 + a3);
            v = acc + __shfl_xor(acc, 32, 64);
        }
        float z = v * beta[s];
        #pragma unroll
        for (int m = 16; m >= 1; m >>= 1) z += __shfl_xor(z, m, 64);
        if (tid == 0) out[BSZ] = z * (float)BSZ;
    }
}

// ===========================================================================
// FALLBACK PATH: R5 fused kernel verbatim (42.3 us proven) if ws is too small
// ===========================================================================
#define FB_BLOCK 128
#define FB_CHAIN_BLOCKS 256
#define FB_REDUCE_BLOCKS 4000
#define FB_DEPTH 6

__device__ __forceinline__ void fb_issue_load(const float* src_tok, float* lds_base, int lane) {
    const int r  = lane >> 3;
    const int c0 = (lane & 7) * 4;
    #pragma unroll
    for (int j = 0; j < 4; ++j) {
        const float* src = src_tok + (size_t)(j * 8 + r) * ((size_t)VOC * RNK) + c0;
        __builtin_amdgcn_global_load_lds((as1_cvp)src, (as3_vp)(lds_base + j * 256), 16, 0, 0);
    }
}

__global__ __launch_bounds__(FB_BLOCK) void fb_fused_kernel(const float* __restrict__ core,
                                                            const int* __restrict__ y,
                                                            const float* __restrict__ alpha,
                                                            const float* __restrict__ beta,
                                                            float* __restrict__ out,
                                                            float* __restrict__ gm) {
    __shared__ float shmem[2 * FB_DEPTH * 1024 + RNK];
    if (blockIdx.x < FB_CHAIN_BLOCKS) {
        const int tid  = threadIdx.x;
        const int lane = tid & 63;
        const int w    = tid >> 6;
        const int s    = lane & 31;
        const int half = lane >> 5;
        const int row  = blockIdx.x * 2 + w;
        float* mybuf = shmem + w * (FB_DEPTH * 1024);

        int   ytok  = (lane < SEQ) ? y[row * SEQ + lane] : 0;
        float state = alpha[s];
        float betav = beta[s];
        asm volatile("s_waitcnt vmcnt(0)" ::: "memory");

        #pragma unroll
        for (int pt = 0; pt < FB_DEPTH; ++pt) {
            const int tok = __shfl(ytok, pt, 64);
            fb_issue_load(core + (size_t)tok * RNK, mybuf + pt * 1024, lane);
        }
        #pragma unroll
        for (int t = 0; t < SEQ; ++t) {
            if      (t <= SEQ - 6) asm volatile("s_waitcnt vmcnt(20)" ::: "memory");
            else if (t == SEQ - 5) asm volatile("s_waitcnt vmcnt(16)" ::: "memory");
            else if (t == SEQ - 4) asm volatile("s_waitcnt vmcnt(12)" ::: "memory");
            else if (t == SEQ - 3) asm volatile("s_waitcnt vmcnt(8)"  ::: "memory");
            else if (t == SEQ - 2) asm volatile("s_waitcnt vmcnt(4)"  ::: "memory");
            else                   asm volatile("s_waitcnt vmcnt(0)"  ::: "memory");
            __builtin_amdgcn_sched_barrier(0);

            if (t + FB_DEPTH < SEQ) {
                const int tok = __shfl(ytok, t + FB_DEPTH, 64);
                fb_issue_load(core + (size_t)tok * RNK,
                              mybuf + ((t + FB_DEPTH) % FB_DEPTH) * 1024, lane);
            }
            const float* M = mybuf + (t % FB_DEPTH) * 1024;
            float a0 = 0.f, a1 = 0.f, a2 = 0.f, a3 = 0.f;
            #pragma unroll
            for (int i = 0; i < 16; i += 4) {
                a0 = fmaf(__shfl(state, half * 16 + i + 0, 64), M[(half * 16 + i + 0) * 32 + s], a0);
                a1 = fmaf(__shfl(state, half * 16 + i + 1, 64), M[(half * 16 + i + 1) * 32 + s], a1);
                a2 = fmaf(__shfl(state, half * 16 + i + 2, 64), M[(half * 16 + i + 2) * 32 + s], a2);
                a3 = fmaf(__shfl(state, half * 16 + i + 3, 64), M[(half * 16 + i + 3) * 32 + s], a3);
            }
            const float acc = (a0 + a1) + (a2 + a3);
            state = acc + __shfl_xor(acc, 32, 64);
        }
        float p = state * betav;
        #pragma unroll
        for (int m = 16; m >= 1; m >>= 1) p += __shfl_xor(p, m, 64);
        if (lane == 0) out[row] = p;
    } else {
        const int bid   = blockIdx.x - FB_CHAIN_BLOCKS;
        const int r     = bid & 31;
        const int chunk = bid >> 5;
        const int tid   = threadIdx.x;
        const float4* slab = (const float4*)(core + (size_t)r * VOC * RNK);
        const int base = chunk * 2048 + tid;
        float a0 = 0.f, a1 = 0.f, a2 = 0.f, a3 = 0.f;
        #pragma unroll
        for (int i = 0; i < 16; ++i) {
            float4 v = slab[base + i * 128];
            a0 += v.x; a1 += v.y; a2 += v.z; a3 += v.w;
        }
        float* ml = shmem;
        if (tid < RNK) ml[tid] = 0.f;
        __syncthreads();
        const int s0 = (tid & 7) * 4;
        atomicAdd(&ml[s0 + 0], a0);
        atomicAdd(&ml[s0 + 1], a1);
        atomicAdd(&ml[s0 + 2], a2);
        atomicAdd(&ml[s0 + 3], a3);
        __syncthreads();
        if (tid < RNK) atomicAdd(&gm[r * RNK + tid], ml[tid]);
    }
}

__global__ void fb_zchain_kernel(const float* __restrict__ gm,
                                 const float* __restrict__ alpha,
                                 const float* __restrict__ beta,
                                 float* __restrict__ out) {
    const int lane = threadIdx.x & 63;
    const int s    = lane & 31;
    const int half = lane >> 5;
    float col[16];
    #pragma unroll
    for (int i = 0; i < 16; ++i) col[i] = gm[(half * 16 + i) * RNK + s];
    float v = alpha[s];
    #pragma unroll
    for (int t = 0; t < SEQ; ++t) {
        float a0 = 0.f, a1 = 0.f, a2 = 0.f, a3 = 0.f;
        #pragma unroll
        for (int i = 0; i < 16; i += 4) {
            a0 = fmaf(__shfl(v, half * 16 + i + 0, 64), col[i + 0], a0);
            a1 = fmaf(__shfl(v, half * 16 + i + 1, 64), col[i + 1], a1);
            a2 = fmaf(__shfl(v, half * 16 + i + 2, 64), col[i + 2], a2);
            a3 = fmaf(__shfl(v, half * 16 + i + 3, 64), col[i + 3], a3);
        }
        const float acc = (a0 + a1) + (a2 + a3);
        v = acc + __shfl_xor(acc, 32, 64);
    }
    float z = v * beta[s];
    #pragma unroll
    for (int m = 16; m >= 1; m >>= 1) z += __shfl_xor(z, m, 64);
    if (lane == 0) out[BSZ] = z * (float)BSZ;
}

// ===========================================================================

extern "C" void kernel_launch(void* const* d_in, const int* in_sizes, int n_in,
                              void* d_out, int out_size, void* d_ws, size_t ws_size,
                              hipStream_t stream) {
    const int*   y     = (const int*)d_in[0];
    const float* alpha = (const float*)d_in[1];
    const float* beta  = (const float*)d_in[2];
    const float* core  = (const float*)d_in[3];
    float*          out    = (float*)d_out;
    float*          gm     = (float*)d_ws;                      // 1024 f32
    unsigned*       bitmap = (unsigned*)(gm + 1024);            // 1024 u32
    unsigned short* staged = (unsigned short*)(bitmap + 1024);  // VOC*1024 bf16

    if (ws_size >= WS_NEEDED) {
        hipMemsetAsync(d_ws, 0, 8192, stream);                  // gm + bitmap
        bitmap_kernel<<<48, 256, 0, stream>>>(y, bitmap);
        reduce_stage_kernel<<<RED_BLOCKS, RED_THREADS, 0, stream>>>(core, gm, bitmap, staged);
        chainz_staged_kernel<<<BSZ + 1, 64, 0, stream>>>(staged, y, alpha, beta, gm, out);
    } else {
        hipMemsetAsync(gm, 0, RNK * RNK * sizeof(float), stream);
        fb_fused_kernel<<<FB_CHAIN_BLOCKS + FB_REDUCE_BLOCKS, FB_BLOCK, 0, stream>>>(
            core, y, alpha, beta, out, gm);
        fb_zchain_kernel<<<1, 64, 0, stream>>>(gm, alpha, beta, out);
    }
}